// Round 1
// 754.639 us; speedup vs baseline: 1.1593x; 1.1593x over previous
//
#include <hip/hip_runtime.h>
#include <cstdint>
#include <cstddef>

typedef __bf16 bf16_t;
typedef __bf16 bf16x8 __attribute__((ext_vector_type(8)));
typedef __bf16 bf16x4 __attribute__((ext_vector_type(4)));
typedef __bf16 bf16x2 __attribute__((ext_vector_type(2)));
typedef float f32x4 __attribute__((ext_vector_type(4)));

#define A_TOTAL 262144
#define NMAP    131072

// ---------------- W1 slices f32 -> bf16 ------------------------------------
// slices: 0=map_W1a(qubit) 1=map_W1b(qpu) 2=sch_W1a(gate) 3=sch_W1b(time)
__global__ __launch_bounds__(256) void k_w1b16(
    const float* __restrict__ mW1, const float* __restrict__ sW1,
    bf16_t* __restrict__ dst) {
  int e = blockIdx.x * 256 + threadIdx.x;     // 0..262143
  int slice = e >> 16, idx = e & 65535;
  int n = idx >> 8, k = idx & 255;
  float v;
  switch (slice) {
    case 0:  v = mW1[n * 512 + k]; break;
    case 1:  v = mW1[n * 512 + 256 + k]; break;
    case 2:  v = sW1[n * 512 + k]; break;
    default: v = sW1[n * 512 + 256 + k]; break;
  }
  dst[e] = (bf16_t)v;
}

// ---------------- W2 -> extended weights [272][256] per table --------------
__global__ __launch_bounds__(256) void k_w2ext(
    const float* __restrict__ mW2, const float* __restrict__ sW2,
    bf16_t* __restrict__ wext) {
  int row = blockIdx.x, tab = blockIdx.y, k = threadIdx.x;
  const float* W2 = tab ? sW2 : mW2;
  bf16_t v = (row < 256) ? (bf16_t)W2[row * 256 + k] : (bf16_t)0.f;
  wext[(size_t)tab * 272 * 256 + (size_t)row * 256 + k] = v;
}

// ---------------- column partial sums of all_embeddings [131072][256] ------
__global__ __launch_bounds__(256) void k_mean(const float* __restrict__ A,
                                              float* __restrict__ part) {
  int t = threadIdx.x, b = blockIdx.x;        // 256 blocks x 512 rows
  const float* base = A + (size_t)b * 512 * 256 + t;
  float s = 0.f;
  for (int r = 0; r < 512; ++r) s += base[(size_t)r * 256];
  part[b * 256 + t] = s;
}

// ---------------- g -> query MLP -> q -> qk -> qw rows of Wext -------------
__global__ __launch_bounds__(256) void k_front(
    const float* __restrict__ meanPart,
    const float* __restrict__ qgW1, const float* __restrict__ qgb1,
    const float* __restrict__ qgW2, const float* __restrict__ qgb2,
    const float* __restrict__ Wq,  const float* __restrict__ bq,
    const float* __restrict__ Wk,
    const float* __restrict__ mW2, const float* __restrict__ sW2,
    bf16_t* __restrict__ wext) {
  __shared__ float g[256], h1[256], qry[256], qv[256];
  __shared__ float qks[4][256];
  int t = threadIdx.x;
  float s = 0.f;
  for (int b = 0; b < 256; ++b) s += meanPart[b * 256 + t];
  g[t] = s * (1.0f / 131072.0f);
  __syncthreads();
  {
    const f32x4* row = (const f32x4*)(qgW1 + (size_t)t * 256);
    float acc = 0.f;
    for (int k = 0; k < 64; ++k) {
      f32x4 w = row[k];
      acc += w[0] * g[4 * k] + w[1] * g[4 * k + 1] + w[2] * g[4 * k + 2] + w[3] * g[4 * k + 3];
    }
    h1[t] = fmaxf(acc + qgb1[t], 0.f);
  }
  __syncthreads();
  {
    const f32x4* row = (const f32x4*)(qgW2 + (size_t)t * 256);
    float acc = 0.f;
    for (int k = 0; k < 64; ++k) {
      f32x4 w = row[k];
      acc += w[0] * h1[4 * k] + w[1] * h1[4 * k + 1] + w[2] * h1[4 * k + 2] + w[3] * h1[4 * k + 3];
    }
    qry[t] = acc + qgb2[t];
  }
  __syncthreads();
  {
    const f32x4* row = (const f32x4*)(Wq + (size_t)t * 256);
    float acc = 0.f;
    for (int k = 0; k < 64; ++k) {
      f32x4 w = row[k];
      acc += w[0] * qry[4 * k] + w[1] * qry[4 * k + 1] + w[2] * qry[4 * k + 2] + w[3] * qry[4 * k + 3];
    }
    qv[t] = acc + bq[t];
  }
  __syncthreads();
  for (int h = 0; h < 4; ++h) {
    float acc = 0.f;
    for (int d = 0; d < 64; ++d) acc += qv[h * 64 + d] * Wk[(size_t)(h * 64 + d) * 256 + t];
    qks[h][t] = acc * 0.125f;
  }
  __syncthreads();
  for (int tab = 0; tab < 2; ++tab) {
    const float* W2 = tab ? sW2 : mW2;
    float acc0 = 0.f, acc1 = 0.f, acc2 = 0.f, acc3 = 0.f;
    for (int n = 0; n < 256; ++n) {
      float wv = W2[(size_t)n * 256 + t];
      acc0 += qks[0][n] * wv;
      acc1 += qks[1][n] * wv;
      acc2 += qks[2][n] * wv;
      acc3 += qks[3][n] * wv;
    }
    bf16_t* dst = wext + (size_t)tab * 272 * 256;
    dst[(256 + 0) * 256 + t] = (bf16_t)acc0;
    dst[(256 + 1) * 256 + t] = (bf16_t)acc1;
    dst[(256 + 2) * 256 + t] = (bf16_t)acc2;
    dst[(256 + 3) * 256 + t] = (bf16_t)acc3;
  }
}

// ---------------- GEMM (direct, merged 2 problem halves) -------------------
// C[M][256] = bf16( A_f32 @ W^T + bias ). 512 thr = 8 waves (2 row x 4 col),
// tile 128x256, K=256. Output staged in LDS, written as flat coalesced copy.
__global__ __launch_bounds__(512, 4) void gemm_direct3(
    const float* __restrict__ A0, int M0, const bf16_t* __restrict__ W0,
    const float* __restrict__ b0, bf16_t* __restrict__ C0, int split,
    const float* __restrict__ A1, int M1, const bf16_t* __restrict__ W1,
    const float* __restrict__ b1, bf16_t* __restrict__ C1) {
  __shared__ __align__(16) bf16_t Xo[128][264];   // 67584 B
  int blk = blockIdx.x;
  const float* A; int M; const bf16_t* W; const float* bias; bf16_t* C; int bid;
  if (blk < split) { A = A0; M = M0; W = W0; bias = b0; C = C0; bid = blk; }
  else             { A = A1; M = M1; W = W1; bias = b1; C = C1; bid = blk - split; }
  int t = threadIdx.x;
  int w = t >> 6, lane = t & 63;
  int lm = lane & 15, q = lane >> 4;
  int mloc0 = (w & 1) * 64;
  int m0 = bid * 128 + mloc0;
  int c0 = (w >> 1) * 64;
  int rows[4];
#pragma unroll
  for (int i = 0; i < 4; ++i) {
    int m = m0 + i * 16 + lm;
    rows[i] = m < M ? m : M - 1;
  }
  f32x4 acc[4][4] = {};
#pragma unroll
  for (int kt = 0; kt < 8; ++kt) {
    int k0 = kt * 32 + q * 8;
    bf16x8 b[4];
#pragma unroll
    for (int j = 0; j < 4; ++j)
      b[j] = *(const bf16x8*)(W + (size_t)(c0 + j * 16 + lm) * 256 + k0);
#pragma unroll
    for (int i = 0; i < 4; ++i) {
      const float* src = A + (size_t)rows[i] * 256 + k0;
      f32x4 lo = *(const f32x4*)src;
      f32x4 hi = *(const f32x4*)(src + 4);
      bf16x8 a;
#pragma unroll
      for (int x = 0; x < 4; ++x) { a[x] = (bf16_t)lo[x]; a[x + 4] = (bf16_t)hi[x]; }
#pragma unroll
      for (int j = 0; j < 4; ++j)
        acc[i][j] = __builtin_amdgcn_mfma_f32_16x16x32_bf16(a, b[j], acc[i][j], 0, 0, 0);
    }
  }
  // stage bias-added bf16 outputs in LDS
#pragma unroll
  for (int j = 0; j < 4; ++j) {
    int col = c0 + j * 16 + lm;
    float bb = bias ? bias[col] : 0.f;
#pragma unroll
    for (int i = 0; i < 4; ++i)
#pragma unroll
      for (int r = 0; r < 4; ++r)
        Xo[mloc0 + i * 16 + q * 4 + r][col] = (bf16_t)(acc[i][j][r] + bb);
  }
  __syncthreads();
  // flat coalesced write: 128 rows x 512 B = 64 KiB tile
  size_t tile0 = (size_t)bid * 128;
  const char* lds = (const char*)&Xo[0][0];
#pragma unroll
  for (int s = 0; s < 8; ++s) {
    int flat = s * 8192 + t * 16;
    int row = flat >> 9, colb = flat & 511;
    if (tile0 + (size_t)row < (size_t)M) {
      uint4 v = *(const uint4*)(lds + row * 528 + colb);
      *(uint4*)((char*)C + tile0 * 512 + (size_t)flat) = v;
    }
  }
}

// ---------------- GEMM (gather, merged halves) + fused scores --------------
// 256 thr = 4 waves (col split), tile 64 rows x 256 cols, full-K LDS staging.
// X = relu(Pa[ia]+Pb[ib]); output restaged in LDS, flat coalesced write.
__global__ __launch_bounds__(256, 4) void gemm_gather3(
    const bf16_t* __restrict__ Pa0, const bf16_t* __restrict__ Pb0,
    const int* __restrict__ idxA0, const int* __restrict__ idxB0,
    const bf16_t* __restrict__ Wext0, const float* __restrict__ bias0,
    const bf16_t* __restrict__ Pa1, const bf16_t* __restrict__ Pb1,
    const int* __restrict__ idxA1, const int* __restrict__ idxB1,
    const bf16_t* __restrict__ Wext1, const float* __restrict__ bias1,
    bf16_t* __restrict__ C,
    float* __restrict__ scores, float* __restrict__ partMax) {
  __shared__ __align__(16) bf16_t X[64][264];    // 33792 B, reused for output
  __shared__ float sred[4];
  int blk = blockIdx.x;
  int half = blk >> 11, bid = blk & 2047;
  const bf16_t* Pa; const bf16_t* Pb; const int* idxA; const int* idxB;
  const bf16_t* Wext; const float* bias;
  if (half == 0) { Pa = Pa0; Pb = Pb0; idxA = idxA0; idxB = idxB0; Wext = Wext0; bias = bias0; }
  else           { Pa = Pa1; Pb = Pb1; idxA = idxA1; idxB = idxB1; Wext = Wext1; bias = bias1; }
  int scoreBase = half * NMAP;
  int pmBase = half * 2048;

  int t = threadIdx.x;
  int w = t >> 6, lane = t & 63;
  int lm = lane & 15, q = lane >> 4;
  int cw = w * 64;
  int r = t >> 2, qa = t & 3;        // 4 threads per row
  int row0 = bid * 64;
  int ia = idxA[row0 + r], ib = idxB[row0 + r];
  const bf16_t* paRow = Pa + (size_t)ia * 256;
  const bf16_t* pbRow = Pb + (size_t)ib * 256;

  // full-K staging: 16 independent 16B loads, then one relu/convert pass
  bf16x8 va[8], vb[8];
#pragma unroll
  for (int s = 0; s < 8; ++s) {
    int ch = s * 4 + qa;             // chunk of 8 elems; 4 lanes -> 64B runs
    va[s] = *(const bf16x8*)(paRow + ch * 8);
    vb[s] = *(const bf16x8*)(pbRow + ch * 8);
  }
#pragma unroll
  for (int s = 0; s < 8; ++s) {
    int ch = s * 4 + qa;
    bf16x8 x;
#pragma unroll
    for (int e = 0; e < 8; ++e)
      x[e] = (bf16_t)fmaxf((float)va[s][e] + (float)vb[s][e], 0.f);
    *(bf16x8*)&X[r][ch * 8] = x;
  }
  __syncthreads();

  f32x4 acc[4][4] = {};
  f32x4 accs[4] = {};
  bool doScore = (w == 0);
#pragma unroll
  for (int kt = 0; kt < 8; ++kt) {
    int kl = kt * 32 + q * 8;
    bf16x8 a[4];
#pragma unroll
    for (int i = 0; i < 4; ++i)
      a[i] = *(const bf16x8*)&X[i * 16 + lm][kl];
#pragma unroll
    for (int j = 0; j < 4; ++j) {
      bf16x8 b = *(const bf16x8*)(Wext + (size_t)(cw + j * 16 + lm) * 256 + kl);
#pragma unroll
      for (int i = 0; i < 4; ++i)
        acc[i][j] = __builtin_amdgcn_mfma_f32_16x16x32_bf16(a[i], b, acc[i][j], 0, 0, 0);
    }
    if (doScore) {
      bf16x8 bs = *(const bf16x8*)(Wext + (size_t)(256 + lm) * 256 + kl);
#pragma unroll
      for (int i = 0; i < 4; ++i)
        accs[i] = __builtin_amdgcn_mfma_f32_16x16x32_bf16(a[i], bs, accs[i], 0, 0, 0);
    }
  }
  __syncthreads();                   // all X reads done; reuse X for output
  // stage bias-added bf16 keys back into X
#pragma unroll
  for (int j = 0; j < 4; ++j) {
    int col = cw + j * 16 + lm;
    float bb = bias[col];
#pragma unroll
    for (int i = 0; i < 4; ++i)
#pragma unroll
      for (int rr = 0; rr < 4; ++rr)
        X[i * 16 + q * 4 + rr][col] = (bf16_t)(acc[i][j][rr] + bb);
  }
  // scores epilogue (wave 0; lanes lm<4 hold head lm)
  float hmax = -3.4e38f;
  if (doScore) {
    if (lm < 4) {
#pragma unroll
      for (int i = 0; i < 4; ++i)
#pragma unroll
        for (int rr = 0; rr < 4; ++rr) {
          int m = i * 16 + q * 4 + rr;
          float v = accs[i][rr];
          scores[(size_t)lm * A_TOTAL + scoreBase + row0 + m] = v;
          hmax = fmaxf(hmax, v);
        }
    }
    float m1 = fmaxf(hmax, __shfl_xor(hmax, 16));
    float m2 = fmaxf(m1, __shfl_xor(m1, 32));
    if (lane < 4) sred[lane] = m2;
  }
  __syncthreads();
  // flat coalesced write: 64 rows x 512 B = 32 KiB tile
  size_t gRow0 = (size_t)(half * NMAP + row0);
  const char* lds = (const char*)&X[0][0];
#pragma unroll
  for (int s = 0; s < 8; ++s) {
    int flat = s * 4096 + t * 16;
    int row = flat >> 9, colb = flat & 511;
    uint4 v = *(const uint4*)(lds + row * 528 + colb);
    *(uint4*)((char*)C + gRow0 * 512 + (size_t)flat) = v;
  }
  if (t < 4) partMax[t * 4096 + pmBase + bid] = sred[t];
}

// ---------------- per-head max over 4096 block partials --------------------
__global__ __launch_bounds__(256) void k_smax2(const float* __restrict__ pM,
                                               float* __restrict__ Mh) {
  int t = threadIdx.x;
  __shared__ float red[256];
  for (int h = 0; h < 4; ++h) {
    float m = -3.4e38f;
    for (int i = t; i < 4096; i += 256) m = fmaxf(m, pM[h * 4096 + i]);
    red[t] = m;
    __syncthreads();
    for (int s = 128; s > 0; s >>= 1) {
      if (t < s) red[t] = fmaxf(red[t], red[t + s]);
      __syncthreads();
    }
    if (t == 0) Mh[h] = red[0];
    __syncthreads();
  }
}

__global__ __launch_bounds__(256) void k_ssum(const float* __restrict__ scores,
                                              const float* __restrict__ Mh,
                                              float* __restrict__ part) {
  int b = blockIdx.x, t = threadIdx.x;    // 256 blocks, head = b>>6
  float m = Mh[b >> 6];
  const float* base = scores + (size_t)b * 4096;
  float s = 0.f;
  for (int i = 0; i < 16; ++i) s += __expf(base[i * 256 + t] - m);
  __shared__ float red[256];
  red[t] = s;
  __syncthreads();
  for (int st = 128; st > 0; st >>= 1) {
    if (t < st) red[t] += red[t + st];
    __syncthreads();
  }
  if (t == 0) part[b] = red[0];
}

__global__ __launch_bounds__(256) void k_ssum2(const float* __restrict__ part,
                                               float* __restrict__ invS) {
  int t = threadIdx.x;
  __shared__ float red[256];
  red[t] = part[t];
  __syncthreads();
  for (int s = 32; s > 0; s >>= 1) {
    if ((t & 63) < s) red[t] += red[t + s];
    __syncthreads();
  }
  if ((t & 63) == 0) invS[t >> 6] = 1.0f / red[t];
}

// ---------------- u[h] = sum_a w[h,a] * keys[a] (bf16x8 loads) -------------
__global__ __launch_bounds__(256) void k_u(
    const bf16_t* __restrict__ keys, const float* __restrict__ scores,
    const float* __restrict__ Mh, const float* __restrict__ invS,
    float* __restrict__ u) {
  __shared__ float wl[4][512];
  __shared__ float uloc[8][4][256];     // 32 KiB
  int t = threadIdx.x;
  int a0 = blockIdx.x * 512;            // 512 blocks x 512 rows
#pragma unroll
  for (int i = 0; i < 8; ++i) {
    int e = i * 256 + t;                // 0..2047
    int h = e >> 9, rr = e & 511;
    wl[h][rr] = __expf(scores[(size_t)h * A_TOTAL + a0 + rr] - Mh[h]) * invS[h];
  }
  __syncthreads();
  int tc = t & 31, rh = t >> 5;         // 32 col-threads x 8 cols; 8 row groups
  float acc[4][8] = {};
  for (int rr = 0; rr < 64; ++rr) {
    int al = rh * 64 + rr;
    bf16x8 kv = *(const bf16x8*)(keys + (size_t)(a0 + al) * 256 + tc * 8);
    float f[8];
#pragma unroll
    for (int e = 0; e < 8; ++e) f[e] = (float)kv[e];
#pragma unroll
    for (int h = 0; h < 4; ++h) {
      float wv = wl[h][al];
#pragma unroll
      for (int e = 0; e < 8; ++e) acc[h][e] += wv * f[e];
    }
  }
#pragma unroll
  for (int h = 0; h < 4; ++h)
#pragma unroll
    for (int e = 0; e < 8; ++e) uloc[rh][h][tc * 8 + e] = acc[h][e];
  __syncthreads();
#pragma unroll
  for (int h = 0; h < 4; ++h) {
    float v = 0.f;
#pragma unroll
    for (int g = 0; g < 8; ++g) v += uloc[g][h][t];
    atomicAdd(&u[h * 256 + t], v);
  }
}

// ---------------- ctx = u @ Wv_h^T + bv ; attn_out = ctx @ Wo^T + bo -------
__global__ __launch_bounds__(256) void k_attn(
    const float* __restrict__ u, const float* __restrict__ Wv,
    const float* __restrict__ bv, const float* __restrict__ Wo,
    const float* __restrict__ bo, float* __restrict__ attn_out,
    bf16_t* __restrict__ attn_pad) {
  __shared__ float ctx[256];
  int t = threadIdx.x;
  int h = t >> 6;
  const float* uh = u + h * 256;
  {
    const f32x4* row = (const f32x4*)(Wv + (size_t)t * 256);
    float acc = 0.f;
    for (int k = 0; k < 64; ++k) {
      f32x4 w = row[k];
      acc += w[0] * uh[4 * k] + w[1] * uh[4 * k + 1] + w[2] * uh[4 * k + 2] + w[3] * uh[4 * k + 3];
    }
    ctx[t] = acc + bv[t];
  }
  __syncthreads();
  {
    const f32x4* row = (const f32x4*)(Wo + (size_t)t * 256);
    float acc = 0.f;
    for (int k = 0; k < 64; ++k) {
      f32x4 w = row[k];
      acc += w[0] * ctx[4 * k] + w[1] * ctx[4 * k + 1] + w[2] * ctx[4 * k + 2] + w[3] * ctx[4 * k + 3];
    }
    float v = acc + bo[t];
    attn_out[t] = v;
    attn_pad[t] = (bf16_t)v;
#pragma unroll
    for (int i = 1; i < 16; ++i) attn_pad[i * 256 + t] = (bf16_t)0.f;
  }
}

// ---------------- logits[a] = keys[a] . attn_out (MFMA) + block max --------
__global__ __launch_bounds__(256) void k_logits2(
    const bf16_t* __restrict__ keys, const bf16_t* __restrict__ attn_pad,
    float* __restrict__ out_logits, float* __restrict__ blockMax) {
  int t = threadIdx.x;
  int w = t >> 6, lane = t & 63;
  int lm = lane & 15, q = lane >> 4;
  int m0 = blockIdx.x * 256 + w * 64;
  bf16x8 b[8];
#pragma unroll
  for (int kt = 0; kt < 8; ++kt)
    b[kt] = *(const bf16x8*)(attn_pad + lm * 256 + kt * 32 + q * 8);
  f32x4 acc[4] = {};
#pragma unroll
  for (int i = 0; i < 4; ++i) {
    const bf16_t* arow = keys + (size_t)(m0 + i * 16 + lm) * 256 + q * 8;
#pragma unroll
    for (int kt = 0; kt < 8; ++kt) {
      bf16x8 a = *(const bf16x8*)(arow + kt * 32);
      acc[i] = __builtin_amdgcn_mfma_f32_16x16x32_bf16(a, b[kt], acc[i], 0, 0, 0);
    }
  }
  float lmax = -3.4e38f;
  if (lm == 0) {
#pragma unroll
    for (int i = 0; i < 4; ++i) {
      *(f32x4*)(out_logits + m0 + i * 16 + q * 4) = acc[i];
#pragma unroll
      for (int rr = 0; rr < 4; ++rr) lmax = fmaxf(lmax, acc[i][rr]);
    }
  }
  float m1 = fmaxf(lmax, __shfl_xor(lmax, 16));
  float m2 = fmaxf(m1, __shfl_xor(m1, 32));
  __shared__ float red[4];
  if (lane == 0) red[w] = m2;
  __syncthreads();
  if (t == 0)
    blockMax[blockIdx.x] = fmaxf(fmaxf(red[0], red[1]), fmaxf(red[2], red[3]));
}

__global__ __launch_bounds__(256) void k_lred1(const float* __restrict__ bm,
                                               float* __restrict__ Ml) {
  int t = threadIdx.x;
  float m = -3.4e38f;
  for (int i = t; i < 1024; i += 256) m = fmaxf(m, bm[i]);
  __shared__ float red[256];
  red[t] = m;
  __syncthreads();
  for (int s = 128; s > 0; s >>= 1) {
    if (t < s) red[t] = fmaxf(red[t], red[t + s]);
    __syncthreads();
  }
  if (t == 0) Ml[0] = red[0];
}

__global__ __launch_bounds__(256) void k_lsum(const float* __restrict__ logits,
                                              const float* __restrict__ Ml,
                                              float* __restrict__ part) {
  int t = threadIdx.x, b = blockIdx.x;   // 512 blocks x 512 elems
  float m = Ml[0];
  float s = __expf(logits[b * 512 + t] - m) + __expf(logits[b * 512 + 256 + t] - m);
  __shared__ float red[256];
  red[t] = s;
  __syncthreads();
  for (int st = 128; st > 0; st >>= 1) {
    if (t < st) red[t] += red[t + st];
    __syncthreads();
  }
  if (t == 0) part[b] = red[0];
}

__global__ __launch_bounds__(256) void k_lred2(const float* __restrict__ part,
                                               float* __restrict__ invSl) {
  int t = threadIdx.x;
  float s = part[t] + part[t + 256];
  __shared__ float red[256];
  red[t] = s;
  __syncthreads();
  for (int st = 128; st > 0; st >>= 1) {
    if (t < st) red[t] += red[t + st];
    __syncthreads();
  }
  if (t == 0) invSl[0] = 1.0f / red[0];
}

__global__ __launch_bounds__(256) void k_probs(const float* __restrict__ logits,
                                               const float* __restrict__ Ml,
                                               const float* __restrict__ invSl,
                                               float* __restrict__ probs) {
  int i = blockIdx.x * 256 + threadIdx.x;
  probs[i] = __expf(logits[i] - Ml[0]) * invSl[0];
}

// ===========================================================================
extern "C" void kernel_launch(void* const* d_in, const int* in_sizes, int n_in,
                              void* d_out, int out_size, void* d_ws, size_t ws_size,
                              hipStream_t stream) {
  const float* qubit_emb = (const float*)d_in[0];
  const float* qpu_emb   = (const float*)d_in[1];
  const float* gate_emb  = (const float*)d_in[2];
  const float* all_emb   = (const float*)d_in[3];
  const float* time_tab  = (const float*)d_in[4];
  const float* map_W1 = (const float*)d_in[5];
  const float* map_b1 = (const float*)d_in[6];
  const float* map_W2 = (const float*)d_in[7];
  const float* map_b2 = (const float*)d_in[8];
  const float* sch_W1 = (const float*)d_in[9];
  const float* sch_b1 = (const float*)d_in[10];
  const float* sch_W2 = (const float*)d_in[11];
  const float* sch_b2 = (const float*)d_in[12];
  const float* qg_W1 = (const float*)d_in[13];
  const float* qg_b1 = (const float*)d_in[14];
  const float* qg_W2 = (const float*)d_in[15];
  const float* qg_b2 = (const float*)d_in[16];
  const float* Wq = (const float*)d_in[17];
  const float* bq = (const float*)d_in[18];
  const float* Wk = (const float*)d_in[19];
  // d_in[20] = attn_bk: per-head constant, softmax-invariant -> unused
  const float* Wv = (const float*)d_in[21];
  const float* bv = (const float*)d_in[22];
  const float* Wo = (const float*)d_in[23];
  const float* bo = (const float*)d_in[24];
  const int* map_qubit  = (const int*)d_in[25];
  const int* map_qpu    = (const int*)d_in[26];
  const int* sched_gate = (const int*)d_in[27];
  const int* sched_time = (const int*)d_in[28];
  (void)in_sizes; (void)n_in; (void)out_size;

  char* ws = (char*)d_ws;
  size_t off = 0;
  auto alloc = [&](size_t b) { size_t r = off; off += (b + 255) & ~(size_t)255; return r; };
  size_t KEYS  = alloc((size_t)A_TOTAL * 256 * 2);   // bf16 keys
  size_t PQ    = alloc((size_t)65536 * 256 * 2);     // bf16 qubit proj
  size_t PG    = alloc((size_t)65536 * 256 * 2);     // bf16 gate proj
  size_t PP    = alloc((size_t)128 * 256 * 2);       // bf16 qpu proj (+b1)
  size_t PT    = alloc((size_t)1024 * 256 * 2);      // bf16 time proj (+b1)
  size_t W1B   = alloc((size_t)4 * 65536 * 2);       // bf16 W1 slices
  size_t WEXT  = alloc((size_t)2 * 272 * 256 * 2);   // bf16 extended W2 (+qw)
  size_t SCORE = alloc((size_t)4 * A_TOTAL * 4);     // f32 scores [4][A]
  size_t MPART = alloc((size_t)256 * 256 * 4);       // mean partials
  size_t APAD  = alloc((size_t)16 * 256 * 2);        // bf16 attn_out padded
  size_t ATTN  = alloc(256 * 4);
  size_t U     = alloc(4 * 256 * 4);
  size_t PMAX  = alloc(4 * 4096 * 4);
  size_t MH    = alloc(4 * 4);
  size_t SINV  = alloc(4 * 4);
  size_t BMAX  = alloc(1024 * 4);
  size_t ML    = alloc(4);
  size_t SLINV = alloc(4);
  size_t LPART = alloc(512 * 4);
  size_t SPART = alloc(256 * 4);
  if (off > ws_size) return;  // insufficient scratch -> loud validation fail

  bf16_t* keysP  = (bf16_t*)(ws + KEYS);
  bf16_t* pqP    = (bf16_t*)(ws + PQ);
  bf16_t* pgP    = (bf16_t*)(ws + PG);
  bf16_t* ppP    = (bf16_t*)(ws + PP);
  bf16_t* ptP    = (bf16_t*)(ws + PT);
  bf16_t* w1bP   = (bf16_t*)(ws + W1B);
  bf16_t* wextP  = (bf16_t*)(ws + WEXT);
  float*  scoreP = (float*)(ws + SCORE);
  float*  mpartP = (float*)(ws + MPART);
  bf16_t* apadP  = (bf16_t*)(ws + APAD);
  float*  attnP  = (float*)(ws + ATTN);
  float*  uP     = (float*)(ws + U);
  float*  pmaxP  = (float*)(ws + PMAX);
  float*  mhP    = (float*)(ws + MH);
  float*  sinvP  = (float*)(ws + SINV);
  float*  bmaxP  = (float*)(ws + BMAX);
  float*  mlP    = (float*)(ws + ML);
  float*  slinvP = (float*)(ws + SLINV);
  float*  lpartP = (float*)(ws + LPART);
  float*  spartP = (float*)(ws + SPART);

  float* probsOut  = (float*)d_out;
  float* logitsOut = probsOut + A_TOTAL;

  hipMemsetAsync(uP, 0, 4 * 256 * 4, stream);

  k_w1b16<<<1024, 256, 0, stream>>>(map_W1, sch_W1, w1bP);
  k_w2ext<<<dim3(272, 2), 256, 0, stream>>>(map_W2, sch_W2, wextP);
  k_mean<<<256, 256, 0, stream>>>(all_emb, mpartP);
  k_front<<<1, 256, 0, stream>>>(mpartP, qg_W1, qg_b1, qg_W2, qg_b2,
                                 Wq, bq, Wk, map_W2, sch_W2, wextP);

  // table projections (layer-1 halves): qubit+gate merged, qpu+time merged
  gemm_direct3<<<1024, 512, 0, stream>>>(
      qubit_emb, 65536, w1bP + 0 * 65536, nullptr, pqP, 512,
      gate_emb,  65536, w1bP + 2 * 65536, nullptr, pgP);
  gemm_direct3<<<9, 512, 0, stream>>>(
      qpu_emb, 64,   w1bP + 1 * 65536, map_b1, ppP, 1,
      time_tab, 1000, w1bP + 3 * 65536, sch_b1, ptP);

  // keys + fused scores (both halves in one dispatch)
  gemm_gather3<<<4096, 256, 0, stream>>>(
      pqP, ppP, map_qubit, map_qpu, wextP, map_b2,
      pgP, ptP, sched_gate, sched_time, wextP + 272 * 256, sch_b2,
      keysP, scoreP, pmaxP);

  // softmax stats over scores
  k_smax2<<<1, 256, 0, stream>>>(pmaxP, mhP);
  k_ssum<<<256, 256, 0, stream>>>(scoreP, mhP, spartP);
  k_ssum2<<<1, 256, 0, stream>>>(spartP, sinvP);

  // weighted key sum -> ctx -> attn_out
  k_u<<<512, 256, 0, stream>>>(keysP, scoreP, mhP, sinvP, uP);
  k_attn<<<1, 256, 0, stream>>>(uP, Wv, bv, Wo, bo, attnP, apadP);

  // logits + global softmax
  k_logits2<<<1024, 256, 0, stream>>>(keysP, apadP, logitsOut, bmaxP);
  k_lred1<<<1, 256, 0, stream>>>(bmaxP, mlP);
  k_lsum<<<512, 256, 0, stream>>>(logitsOut, mlP, lpartP);
  k_lred2<<<1, 256, 0, stream>>>(lpartP, slinvP);
  k_probs<<<1024, 256, 0, stream>>>(logitsOut, mlP, slinvP, probsOut);
}